// Round 6
// baseline (60.593 us; speedup 1.0000x reference)
//
#include <hip/hip_runtime.h>

// BarrelShifter8: out[row][j] = (j >= k) ? P[row][j-k] : 0, k = 4*s2 + 2*s1 + s0.
// mux(s,a,b) on binary {0,1} inputs == (s ? a : b); three mux+shift stages
// compose into one barrel shift by k bits.
//
// History: R1 grid-stride 62.3us; R2 4x unroll regressed; R4 NT stores
// regressed (WRITE 131->150MB); R5 plain/exact-grid 59.8us = 5.3 TB/s
// effective fabric (84% of m13 copy ceiling). R6: S loads were 3x scalar
// dword @ 12B stride (3x line-transactions/byte). Stage S cooperatively:
// 192 dense float4 loads -> LDS (3KB), then stride-3 LDS reads (gcd(3,32)=1
// -> 2-way aliasing = free). Tests whether coalescing density closes the
// remaining 16% to the copy ceiling.

typedef float vfloat4 __attribute__((ext_vector_type(4)));

__global__ __launch_bounds__(256) void barrel_shifter8_kernel(
    const vfloat4* __restrict__ P4,   // (N,8) floats = (N,2) float4
    const vfloat4* __restrict__ S4,   // (N,3) floats viewed as float4[N*3/4]
    vfloat4*       __restrict__ out4, // (N,8) floats = (N,2) float4
    int N)
{
    __shared__ float sS[768];  // 256 rows x 3 floats = 3 KB

    const int t   = threadIdx.x;
    const int blk = blockIdx.x;
    const int row = blk * 256 + t;

    // Cooperative dense S stage: block's S slice = 256*3 floats = 192 float4.
    if (t < 192) {
        long long s4idx = (long long)blk * 192 + t;
        long long nS4 = ((long long)N * 3) / 4;
        if (s4idx < nS4) {
            reinterpret_cast<vfloat4*>(sS)[t] = S4[s4idx];
        }
    }
    __syncthreads();

    if (row >= N) return;

    // Coalesced 32 B row load as two float4 (L1 absorbs the 32B stride).
    vfloat4 a = P4[(size_t)row * 2];
    vfloat4 b = P4[(size_t)row * 2 + 1];

    // S row from LDS: stride-3 across lanes -> bijective mod 32 banks (free).
    float s0 = sS[t * 3 + 0];
    float s1 = sS[t * 3 + 1];
    float s2 = sS[t * 3 + 2];

    int k = (s2 >= 0.5f ? 4 : 0) + (s1 >= 0.5f ? 2 : 0) + (s0 >= 0.5f ? 1 : 0);

    // Pack 8 binary floats -> bits, barrel shift, unpack with constant masks.
    unsigned bits =
        (a.x >= 0.5f ?   1u : 0u) | (a.y >= 0.5f ?   2u : 0u) |
        (a.z >= 0.5f ?   4u : 0u) | (a.w >= 0.5f ?   8u : 0u) |
        (b.x >= 0.5f ?  16u : 0u) | (b.y >= 0.5f ?  32u : 0u) |
        (b.z >= 0.5f ?  64u : 0u) | (b.w >= 0.5f ? 128u : 0u);

    unsigned sh = (bits << k) & 0xFFu;

    vfloat4 o0, o1;
    o0.x = (sh &   1u) ? 1.0f : 0.0f;
    o0.y = (sh &   2u) ? 1.0f : 0.0f;
    o0.z = (sh &   4u) ? 1.0f : 0.0f;
    o0.w = (sh &   8u) ? 1.0f : 0.0f;
    o1.x = (sh &  16u) ? 1.0f : 0.0f;
    o1.y = (sh &  32u) ? 1.0f : 0.0f;
    o1.z = (sh &  64u) ? 1.0f : 0.0f;
    o1.w = (sh & 128u) ? 1.0f : 0.0f;

    out4[(size_t)row * 2]     = o0;
    out4[(size_t)row * 2 + 1] = o1;
}

extern "C" void kernel_launch(void* const* d_in, const int* in_sizes, int n_in,
                              void* d_out, int out_size, void* d_ws, size_t ws_size,
                              hipStream_t stream) {
    const vfloat4* P4 = (const vfloat4*)d_in[0];
    const vfloat4* S4 = (const vfloat4*)d_in[1];
    vfloat4* out4 = (vfloat4*)d_out;

    int N = in_sizes[0] / 8;  // rows

    const int block = 256;
    int grid = (N + block - 1) / block;  // one thread per row

    barrel_shifter8_kernel<<<grid, block, 0, stream>>>(P4, S4, out4, N);
}

// Round 7
// 59.326 us; speedup vs baseline: 1.0213x; 1.0213x over previous
//
#include <hip/hip_runtime.h>

// BarrelShifter8: out[row][j] = (j >= k) ? P[row][j-k] : 0, k = 4*s2 + 2*s1 + s0.
// mux(s,a,b) on binary {0,1} inputs == (s ? a : b); the three mux+shift stages
// compose into a single barrel shift by k bits.
//
// Final form (= R5, best at 59.8 us): one thread per row, exact grid, plain
// float4 loads/stores, scalar S loads. 318 MB logical traffic -> 5.3 TB/s
// effective = 84% of the 6.29 TB/s copy ceiling with a 3-stream mix.
// Falsified alternatives: 4x unroll (R2, occupancy loss), non-temporal
// stores (R4, WRITE 131->150 MB), LDS-staged S (R6, neutral-). Remaining gap
// is the mixed-stream memory wall, not kernel inefficiency.

typedef float vfloat4 __attribute__((ext_vector_type(4)));

__global__ __launch_bounds__(256) void barrel_shifter8_kernel(
    const vfloat4* __restrict__ P4,  // (N, 8) floats viewed as (N, 2) float4
    const float*   __restrict__ S,   // (N, 3), values exactly 0.0f or 1.0f
    vfloat4*       __restrict__ out4,// (N, 8) floats viewed as (N, 2) float4
    int N)
{
    int row = blockIdx.x * 256 + threadIdx.x;
    if (row >= N) return;

    // Coalesced 32 B row load as two float4.
    vfloat4 a = P4[(size_t)row * 2];
    vfloat4 b = P4[(size_t)row * 2 + 1];

    // S row: 3 scalar loads; wave's 64 lanes cover a contiguous, fully-used span.
    const float* s = S + (size_t)row * 3;
    float s0 = s[0];
    float s1 = s[1];
    float s2 = s[2];

    int k = (s2 >= 0.5f ? 4 : 0) + (s1 >= 0.5f ? 2 : 0) + (s0 >= 0.5f ? 1 : 0);

    // Pack the 8 binary floats into bits; barrel shift; unpack with
    // compile-time-constant bit tests (no runtime-indexed reg array).
    unsigned bits =
        (a.x >= 0.5f ?   1u : 0u) | (a.y >= 0.5f ?   2u : 0u) |
        (a.z >= 0.5f ?   4u : 0u) | (a.w >= 0.5f ?   8u : 0u) |
        (b.x >= 0.5f ?  16u : 0u) | (b.y >= 0.5f ?  32u : 0u) |
        (b.z >= 0.5f ?  64u : 0u) | (b.w >= 0.5f ? 128u : 0u);

    unsigned sh = (bits << k) & 0xFFu;

    vfloat4 o0, o1;
    o0.x = (sh &   1u) ? 1.0f : 0.0f;
    o0.y = (sh &   2u) ? 1.0f : 0.0f;
    o0.z = (sh &   4u) ? 1.0f : 0.0f;
    o0.w = (sh &   8u) ? 1.0f : 0.0f;
    o1.x = (sh &  16u) ? 1.0f : 0.0f;
    o1.y = (sh &  32u) ? 1.0f : 0.0f;
    o1.z = (sh &  64u) ? 1.0f : 0.0f;
    o1.w = (sh & 128u) ? 1.0f : 0.0f;

    out4[(size_t)row * 2]     = o0;
    out4[(size_t)row * 2 + 1] = o1;
}

extern "C" void kernel_launch(void* const* d_in, const int* in_sizes, int n_in,
                              void* d_out, int out_size, void* d_ws, size_t ws_size,
                              hipStream_t stream) {
    const vfloat4* P4 = (const vfloat4*)d_in[0];
    const float*   S  = (const float*)d_in[1];
    vfloat4* out4 = (vfloat4*)d_out;

    int N = in_sizes[0] / 8;  // rows

    const int block = 256;
    int grid = (N + block - 1) / block;  // one thread per row, no loop

    barrel_shifter8_kernel<<<grid, block, 0, stream>>>(P4, S, out4, N);
}